// Round 1
// baseline (777.462 us; speedup 1.0000x reference)
//
#include <hip/hip_runtime.h>
#include <math.h>

// Problem constants
constexpr int B_  = 16;
constexpr int P_  = 1024;
constexpr int Q_  = 512;
constexpr int PD_ = 768;   // p_dim
constexpr int QD_ = 768;   // q_dim
constexpr int CD_ = 1536;  // q_dim + p_dim (cand)

#define HUGE_NEG (-1e8f)

// ---------------------------------------------------------------------------
// Shared 128x128 fp32 GEMM micro-kernel: 256 threads, each 8x8 (split 4+4),
// K-tile = 16, LDS rows padded to 132 floats.
// As/Bs layout: [k][i] with row stride 132.
// ---------------------------------------------------------------------------
__device__ __forceinline__ void gemm_compute(const float* __restrict__ As,
                                             const float* __restrict__ Bs,
                                             float (&acc)[2][2][4][4],
                                             int tx, int ty) {
#pragma unroll
  for (int k = 0; k < 16; ++k) {
    const float* ar = As + k * 132;
    const float* br = Bs + k * 132;
    float4 a0 = *(const float4*)(ar + ty * 4);
    float4 a1 = *(const float4*)(ar + 64 + ty * 4);
    float4 b0 = *(const float4*)(br + tx * 4);
    float4 b1 = *(const float4*)(br + 64 + tx * 4);
    float a[2][4] = {{a0.x, a0.y, a0.z, a0.w}, {a1.x, a1.y, a1.z, a1.w}};
    float b[2][4] = {{b0.x, b0.y, b0.z, b0.w}, {b1.x, b1.y, b1.z, b1.w}};
#pragma unroll
    for (int ih = 0; ih < 2; ++ih)
#pragma unroll
      for (int jh = 0; jh < 2; ++jh)
#pragma unroll
        for (int r = 0; r < 4; ++r)
#pragma unroll
          for (int s = 0; s < 4; ++s)
            acc[ih][jh][r][s] += a[ih][r] * b[jh][s];
  }
}

// ---------------------------------------------------------------------------
// K1/K2: C[b][i][j] = sum_k A[b][i][k] * B[b][j][k]   (both K-contiguous)
// lda = ldb = K. Per-batch strides sA/sB/sC (sB=0 => shared B, e.g. W).
// grid = (B, M/128, N/128), block = 256
// ---------------------------------------------------------------------------
__global__ __launch_bounds__(256) void k_gemm_nt(const float* __restrict__ A,
                                                 const float* __restrict__ Bm,
                                                 float* __restrict__ C, int K,
                                                 int ldc, size_t sA, size_t sB,
                                                 size_t sC) {
  __shared__ float As[16 * 132];
  __shared__ float Bs[16 * 132];
  int b = blockIdx.x;
  int i0 = blockIdx.y * 128;
  int j0 = blockIdx.z * 128;
  const float* Ab = A + (size_t)b * sA;
  const float* Bb = Bm + (size_t)b * sB;
  int tid = threadIdx.x;
  int tx = tid & 15, ty = tid >> 4;
  float acc[2][2][4][4] = {};

  for (int k0 = 0; k0 < K; k0 += 16) {
#pragma unroll
    for (int l = 0; l < 2; ++l) {
      int idx = tid + l * 256;
      int i = idx >> 2;
      int kc = (idx & 3) * 4;
      float4 va = *(const float4*)(Ab + (size_t)(i0 + i) * K + k0 + kc);
      As[(kc + 0) * 132 + i] = va.x;
      As[(kc + 1) * 132 + i] = va.y;
      As[(kc + 2) * 132 + i] = va.z;
      As[(kc + 3) * 132 + i] = va.w;
      float4 vb = *(const float4*)(Bb + (size_t)(j0 + i) * K + k0 + kc);
      Bs[(kc + 0) * 132 + i] = vb.x;
      Bs[(kc + 1) * 132 + i] = vb.y;
      Bs[(kc + 2) * 132 + i] = vb.z;
      Bs[(kc + 3) * 132 + i] = vb.w;
    }
    __syncthreads();
    gemm_compute(As, Bs, acc, tx, ty);
    __syncthreads();
  }

  float* Cb = C + (size_t)b * sC;
#pragma unroll
  for (int ih = 0; ih < 2; ++ih)
#pragma unroll
    for (int r = 0; r < 4; ++r) {
      int i = i0 + ih * 64 + ty * 4 + r;
#pragma unroll
      for (int jh = 0; jh < 2; ++jh) {
        float4 o = make_float4(acc[ih][jh][r][0], acc[ih][jh][r][1],
                               acc[ih][jh][r][2], acc[ih][jh][r][3]);
        *(float4*)(Cb + (size_t)i * ldc + j0 + jh * 64 + tx * 4) = o;
      }
    }
}

// ---------------------------------------------------------------------------
// Row stats: softmax over Q for each (b, p) row of affinity, with q_masks.
// One wave per row; block = 4 waves. grid = B*P/4.
// ---------------------------------------------------------------------------
__global__ __launch_bounds__(256) void k_rowstats(const float* __restrict__ aff,
                                                  const int* __restrict__ qmask,
                                                  float* __restrict__ rowmax,
                                                  float* __restrict__ rowsum) {
  int row = blockIdx.x * 4 + (threadIdx.x >> 6);  // [0, B*P)
  int lane = threadIdx.x & 63;
  int b = row >> 10;  // P_ = 1024
  const float* r = aff + (size_t)row * Q_;
  const int* qm = qmask + b * Q_;
  int q0 = lane * 4;
  float4 x = *(const float4*)(r + q0);
  float4 y = *(const float4*)(r + q0 + 256);
  int4 ma = *(const int4*)(qm + q0);
  int4 mb = *(const int4*)(qm + q0 + 256);
  float v[8];
  v[0] = ma.x ? HUGE_NEG : x.x;
  v[1] = ma.y ? HUGE_NEG : x.y;
  v[2] = ma.z ? HUGE_NEG : x.z;
  v[3] = ma.w ? HUGE_NEG : x.w;
  v[4] = mb.x ? HUGE_NEG : y.x;
  v[5] = mb.y ? HUGE_NEG : y.y;
  v[6] = mb.z ? HUGE_NEG : y.z;
  v[7] = mb.w ? HUGE_NEG : y.w;
  float m = v[0];
#pragma unroll
  for (int j = 1; j < 8; ++j) m = fmaxf(m, v[j]);
#pragma unroll
  for (int off = 32; off > 0; off >>= 1) m = fmaxf(m, __shfl_xor(m, off));
  float s = 0.f;
#pragma unroll
  for (int j = 0; j < 8; ++j) s += __expf(v[j] - m);
#pragma unroll
  for (int off = 32; off > 0; off >>= 1) s += __shfl_xor(s, off);
  if (lane == 0) {
    rowmax[row] = m;
    rowsum[row] = s;
  }
}

// ---------------------------------------------------------------------------
// Column stats (softmax over P per (b,q)), two phases.
// Phase 1: partial online (max, sumexp) over 128-row chunks.
// grid = (B, Q/256, 8), block = 256.
// ---------------------------------------------------------------------------
__global__ __launch_bounds__(256) void k_colpart(const float* __restrict__ aff,
                                                 const int* __restrict__ pmask,
                                                 float* __restrict__ pmax_part,
                                                 float* __restrict__ psum_part) {
  int b = blockIdx.x;
  int q = blockIdx.y * 256 + threadIdx.x;
  int z = blockIdx.z;
  const float* ab = aff + ((size_t)b * P_ + z * 128) * Q_ + q;
  const int* pm = pmask + b * P_ + z * 128;
  float m = -INFINITY, s = 0.f;
  for (int p = 0; p < 128; ++p) {
    float v = pm[p] ? HUGE_NEG : ab[(size_t)p * Q_];
    float mn = fmaxf(m, v);
    s = s * __expf(m - mn) + __expf(v - mn);
    m = mn;
  }
  pmax_part[(b * 8 + z) * Q_ + q] = m;
  psum_part[(b * 8 + z) * Q_ + q] = s;
}

// Phase 2: merge 8 partials. grid = (B, Q/256), block = 256.
__global__ __launch_bounds__(256) void k_colmerge(
    const float* __restrict__ pmax_part, const float* __restrict__ psum_part,
    float* __restrict__ colmax, float* __restrict__ colsum) {
  int b = blockIdx.x;
  int q = blockIdx.y * 256 + threadIdx.x;
  float m = -INFINITY;
#pragma unroll
  for (int z = 0; z < 8; ++z) m = fmaxf(m, pmax_part[(b * 8 + z) * Q_ + q]);
  float s = 0.f;
#pragma unroll
  for (int z = 0; z < 8; ++z)
    s += psum_part[(b * 8 + z) * Q_ + q] *
         __expf(pmax_part[(b * 8 + z) * Q_ + q] - m);
  colmax[b * Q_ + q] = m;
  colsum[b * Q_ + q] = s;
}

// ---------------------------------------------------------------------------
// K4: q_to_p[b][q][d] = sum_p softmax_p(aff)[p][q] * p[b][p][d]
// A (direct [k][i]): As[k][i] = exp(masked aff[b][p=k][q=i0+i] - colmax[i]);
// divide by colsum in epilogue. grid = (B, Q/128, PD/128).
// ---------------------------------------------------------------------------
__global__ __launch_bounds__(256) void k_attn_p(
    const float* __restrict__ aff, const float* __restrict__ pmat,
    const int* __restrict__ pmask, const float* __restrict__ colmax,
    const float* __restrict__ colsum, float* __restrict__ out2) {
  __shared__ float As[16 * 132];
  __shared__ float Bs[16 * 132];
  __shared__ float cmax[128];
  __shared__ float csum[128];
  int b = blockIdx.x;
  int i0 = blockIdx.y * 128;  // q
  int j0 = blockIdx.z * 128;  // d
  int tid = threadIdx.x;
  if (tid < 128) {
    cmax[tid] = colmax[b * Q_ + i0 + tid];
    csum[tid] = colsum[b * Q_ + i0 + tid];
  }
  __syncthreads();
  int tx = tid & 15, ty = tid >> 4;
  const float* affb = aff + (size_t)b * P_ * Q_;
  const float* pb = pmat + (size_t)b * P_ * PD_;
  const int* pm = pmask + b * P_;
  float acc[2][2][4][4] = {};

  for (int k0 = 0; k0 < P_; k0 += 16) {
#pragma unroll
    for (int l = 0; l < 2; ++l) {
      int idx = tid + l * 256;
      int kr = idx >> 5;
      int ic = (idx & 31) * 4;
      float4 v = *(const float4*)(affb + (size_t)(k0 + kr) * Q_ + i0 + ic);
      bool msk = pm[k0 + kr] != 0;
      float4 e;
      e.x = __expf((msk ? HUGE_NEG : v.x) - cmax[ic + 0]);
      e.y = __expf((msk ? HUGE_NEG : v.y) - cmax[ic + 1]);
      e.z = __expf((msk ? HUGE_NEG : v.z) - cmax[ic + 2]);
      e.w = __expf((msk ? HUGE_NEG : v.w) - cmax[ic + 3]);
      *(float4*)(As + kr * 132 + ic) = e;
      float4 w4 = *(const float4*)(pb + (size_t)(k0 + kr) * PD_ + j0 + ic);
      *(float4*)(Bs + kr * 132 + ic) = w4;
    }
    __syncthreads();
    gemm_compute(As, Bs, acc, tx, ty);
    __syncthreads();
  }

  float* Cb = out2 + (size_t)b * Q_ * PD_;
#pragma unroll
  for (int ih = 0; ih < 2; ++ih)
#pragma unroll
    for (int r = 0; r < 4; ++r) {
      int il = ih * 64 + ty * 4 + r;
      float inv = 1.0f / csum[il];
#pragma unroll
      for (int jh = 0; jh < 2; ++jh) {
        float4 o = make_float4(acc[ih][jh][r][0] * inv, acc[ih][jh][r][1] * inv,
                               acc[ih][jh][r][2] * inv, acc[ih][jh][r][3] * inv);
        *(float4*)(Cb + (size_t)(i0 + il) * PD_ + j0 + jh * 64 + tx * 4) = o;
      }
    }
}

// ---------------------------------------------------------------------------
// K5: p_to_q[b][p][c] = sum_q softmax_q(aff)[q][p] * cand[b][q][c]
// cand = [q | q_to_p]. A (transpose-stage with exp). grid = (B, P/128, CD/128).
// ---------------------------------------------------------------------------
__global__ __launch_bounds__(256) void k_attn_q(
    const float* __restrict__ aff, const float* __restrict__ qin,
    const float* __restrict__ q2p, const int* __restrict__ qmask,
    const float* __restrict__ rowmax, const float* __restrict__ rowsum,
    float* __restrict__ out1) {
  __shared__ float As[16 * 132];
  __shared__ float Bs[16 * 132];
  __shared__ float rmax[128];
  __shared__ float rsum[128];
  int b = blockIdx.x;
  int i0 = blockIdx.y * 128;  // p
  int j0 = blockIdx.z * 128;  // c
  int tid = threadIdx.x;
  if (tid < 128) {
    rmax[tid] = rowmax[b * P_ + i0 + tid];
    rsum[tid] = rowsum[b * P_ + i0 + tid];
  }
  __syncthreads();
  int tx = tid & 15, ty = tid >> 4;
  const float* affb = aff + (size_t)b * P_ * Q_;
  const int* qm = qmask + b * Q_;
  const float* Bsrc;
  int jb;
  if (j0 < QD_) {
    Bsrc = qin + (size_t)b * Q_ * QD_;
    jb = j0;
  } else {
    Bsrc = q2p + (size_t)b * Q_ * PD_;
    jb = j0 - QD_;
  }
  float acc[2][2][4][4] = {};

  for (int k0 = 0; k0 < Q_; k0 += 16) {
#pragma unroll
    for (int l = 0; l < 2; ++l) {
      int idx = tid + l * 256;
      // A transpose-stage with exp
      int i = idx >> 2;
      int kc = (idx & 3) * 4;
      float4 v = *(const float4*)(affb + (size_t)(i0 + i) * Q_ + k0 + kc);
      float rm = rmax[i];
      As[(kc + 0) * 132 + i] = __expf((qm[k0 + kc + 0] ? HUGE_NEG : v.x) - rm);
      As[(kc + 1) * 132 + i] = __expf((qm[k0 + kc + 1] ? HUGE_NEG : v.y) - rm);
      As[(kc + 2) * 132 + i] = __expf((qm[k0 + kc + 2] ? HUGE_NEG : v.z) - rm);
      As[(kc + 3) * 132 + i] = __expf((qm[k0 + kc + 3] ? HUGE_NEG : v.w) - rm);
      // B direct stage
      int kr = idx >> 5;
      int jc = (idx & 31) * 4;
      float4 w4 = *(const float4*)(Bsrc + (size_t)(k0 + kr) * 768 + jb + jc);
      *(float4*)(Bs + kr * 132 + jc) = w4;
    }
    __syncthreads();
    gemm_compute(As, Bs, acc, tx, ty);
    __syncthreads();
  }

  float* Cb = out1 + (size_t)b * P_ * CD_;
#pragma unroll
  for (int ih = 0; ih < 2; ++ih)
#pragma unroll
    for (int r = 0; r < 4; ++r) {
      int il = ih * 64 + ty * 4 + r;
      float inv = 1.0f / rsum[il];
#pragma unroll
      for (int jh = 0; jh < 2; ++jh) {
        float4 o = make_float4(acc[ih][jh][r][0] * inv, acc[ih][jh][r][1] * inv,
                               acc[ih][jh][r][2] * inv, acc[ih][jh][r][3] * inv);
        *(float4*)(Cb + (size_t)(i0 + il) * CD_ + j0 + jh * 64 + tx * 4) = o;
      }
    }
}

// ---------------------------------------------------------------------------
extern "C" void kernel_launch(void* const* d_in, const int* in_sizes, int n_in,
                              void* d_out, int out_size, void* d_ws,
                              size_t ws_size, hipStream_t stream) {
  const float* p = (const float*)d_in[0];
  const float* q = (const float*)d_in[1];
  const int* pmask = (const int*)d_in[2];
  const int* qmask = (const int*)d_in[3];
  const float* W = (const float*)d_in[4];
  float* out = (float*)d_out;
  float* ws = (float*)d_ws;

  float* qproj = ws;                                 // B*Q*PD
  float* aff = qproj + (size_t)B_ * Q_ * PD_;        // B*P*Q
  float* rowmax = aff + (size_t)B_ * P_ * Q_;        // B*P
  float* rowsum = rowmax + B_ * P_;                  // B*P
  float* colmax = rowsum + B_ * P_;                  // B*Q
  float* colsum = colmax + B_ * Q_;                  // B*Q
  float* pmax_part = colsum + B_ * Q_;               // B*8*Q
  float* psum_part = pmax_part + (size_t)B_ * 8 * Q_;  // B*8*Q

  float* out1 = out;                              // [B,P,1536]
  float* out2 = out + (size_t)B_ * P_ * CD_;      // [B,Q,768]

  // K1: qproj[b,q,p] = sum_d q[b,q,d] * W[p,d]
  k_gemm_nt<<<dim3(B_, Q_ / 128, PD_ / 128), 256, 0, stream>>>(
      q, W, qproj, QD_, PD_, (size_t)Q_ * QD_, 0, (size_t)Q_ * PD_);

  // K2: aff[b,p,q] = sum_d p[b,p,d] * qproj[b,q,d]
  k_gemm_nt<<<dim3(B_, P_ / 128, Q_ / 128), 256, 0, stream>>>(
      p, qproj, aff, PD_, Q_, (size_t)P_ * PD_, (size_t)Q_ * PD_,
      (size_t)P_ * Q_);

  // K3: softmax stats
  k_rowstats<<<B_ * P_ / 4, 256, 0, stream>>>(aff, qmask, rowmax, rowsum);
  k_colpart<<<dim3(B_, Q_ / 256, 8), 256, 0, stream>>>(aff, pmask, pmax_part,
                                                       psum_part);
  k_colmerge<<<dim3(B_, Q_ / 256), 256, 0, stream>>>(pmax_part, psum_part,
                                                     colmax, colsum);

  // K4: q_to_p (out2)
  k_attn_p<<<dim3(B_, Q_ / 128, PD_ / 128), 256, 0, stream>>>(
      aff, p, pmask, colmax, colsum, out2);

  // K5: p_to_q (out1), cand = [q | q_to_p]
  k_attn_q<<<dim3(B_, P_ / 128, CD_ / 128), 256, 0, stream>>>(
      aff, q, out2, qmask, rowmax, rowsum, out1);
}

// Round 2
// 278.352 us; speedup vs baseline: 2.7931x; 2.7931x over previous
//
#include <hip/hip_runtime.h>
#include <math.h>

// Problem constants
constexpr int B_  = 16;
constexpr int P_  = 1024;
constexpr int Q_  = 512;
constexpr int PD_ = 768;   // p_dim
constexpr int QD_ = 768;   // q_dim
constexpr int CD_ = 1536;  // q_dim + p_dim

#define HUGE_NEG (-1e8f)

typedef __attribute__((ext_vector_type(8))) short bf16x8;
typedef __attribute__((ext_vector_type(4))) float f32x4;
typedef __attribute__((ext_vector_type(8))) unsigned short us8;

__device__ __forceinline__ unsigned short f2bf(float f) {
  unsigned int x = __float_as_uint(f);
  x += 0x7FFFu + ((x >> 16) & 1u);   // RNE
  return (unsigned short)(x >> 16);
}
__device__ __forceinline__ float bf2f(unsigned short u) {
  return __uint_as_float(((unsigned int)u) << 16);
}
// async global->LDS DMA, 16B per lane. lds must be wave-uniform chunk base;
// HW writes lds_base + lane*16.
__device__ __forceinline__ void dma16(const void* g, void* l) {
  __builtin_amdgcn_global_load_lds((__attribute__((address_space(1))) void*)g,
                                   (__attribute__((address_space(3))) void*)l,
                                   16, 0, 0);
}

// ---------------------------------------------------------------------------
// split fp32 -> (hi, lo) bf16.  4 elems/thread.
// ---------------------------------------------------------------------------
__global__ __launch_bounds__(256) void k_split(const float* __restrict__ src,
                                               unsigned short* __restrict__ hi,
                                               unsigned short* __restrict__ lo,
                                               int n4) {
  int i = blockIdx.x * 256 + threadIdx.x;
  if (i >= n4) return;
  float4 v = ((const float4*)src)[i];
  float vv[4] = {v.x, v.y, v.z, v.w};
  ushort4 h, l;
  unsigned short* hp = &h.x;
  unsigned short* lp = &l.x;
#pragma unroll
  for (int j = 0; j < 4; ++j) {
    unsigned short hh = f2bf(vv[j]);
    hp[j] = hh;
    lp[j] = f2bf(vv[j] - bf2f(hh));
  }
  ((ushort4*)hi)[i] = h;
  ((ushort4*)lo)[i] = l;
}

// ---------------------------------------------------------------------------
// Transpose fp32 [b][R][C] -> bf16 dst[b][C][R] (with col offset into dst).
// 64x64 tiles. grid = (R/64, C/64, B)
// ---------------------------------------------------------------------------
__global__ __launch_bounds__(256) void k_t2b(const float* __restrict__ src,
                                             unsigned short* __restrict__ dst,
                                             int R, int C, size_t dstBatch,
                                             int colOff) {
  __shared__ unsigned short T[64][72];
  int r0 = blockIdx.x * 64, c0 = blockIdx.y * 64, b = blockIdx.z;
  const float* S = src + (size_t)b * R * C;
  int tid = threadIdx.x;
  int rr = tid >> 4;
  int cc = (tid & 15) * 4;
#pragma unroll
  for (int k = 0; k < 4; ++k) {
    int r = rr + k * 16;
    float4 v = *(const float4*)(S + (size_t)(r0 + r) * C + c0 + cc);
    T[cc + 0][r] = f2bf(v.x);
    T[cc + 1][r] = f2bf(v.y);
    T[cc + 2][r] = f2bf(v.z);
    T[cc + 3][r] = f2bf(v.w);
  }
  __syncthreads();
  int cr = tid >> 2;
  int rc = (tid & 3) * 16;
  unsigned short* D =
      dst + (size_t)b * dstBatch + (size_t)(colOff + c0 + cr) * R + r0;
  *(us8*)(D + rc) = *(us8*)&T[cr][rc];
  *(us8*)(D + rc + 8) = *(us8*)&T[cr][rc + 8];
}

// ---------------------------------------------------------------------------
// WQ[b][q][p] = bf16(exp((pmask[p] ? -HUGE : aff[b][p][q]) - colmax[b][q]))
// grid = (P/64, Q/64, B)
// ---------------------------------------------------------------------------
__global__ __launch_bounds__(256) void k_wq(const float* __restrict__ aff,
                                            const int* __restrict__ pmask,
                                            const float* __restrict__ colmax,
                                            unsigned short* __restrict__ WQ) {
  __shared__ unsigned short T[64][72];
  __shared__ float cmx[64];
  int p0 = blockIdx.x * 64, q0 = blockIdx.y * 64, b = blockIdx.z;
  int tid = threadIdx.x;
  if (tid < 64) cmx[tid] = colmax[b * Q_ + q0 + tid];
  __syncthreads();
  const float* A = aff + (size_t)b * P_ * Q_;
  const int* pm = pmask + b * P_;
  int rr = tid >> 4;
  int cc = (tid & 15) * 4;
#pragma unroll
  for (int k = 0; k < 4; ++k) {
    int r = rr + k * 16;
    int msk = pm[p0 + r];
    float4 v = *(const float4*)(A + (size_t)(p0 + r) * Q_ + q0 + cc);
    float vv[4] = {v.x, v.y, v.z, v.w};
#pragma unroll
    for (int j = 0; j < 4; ++j) {
      float e = __expf((msk ? HUGE_NEG : vv[j]) - cmx[cc + j]);
      T[cc + j][r] = f2bf(e);
    }
  }
  __syncthreads();
  int cr = tid >> 2;
  int rc = (tid & 3) * 16;
  unsigned short* D = WQ + ((size_t)b * Q_ + q0 + cr) * P_ + p0;
  *(us8*)(D + rc) = *(us8*)&T[cr][rc];
  *(us8*)(D + rc + 8) = *(us8*)&T[cr][rc + 8];
}

// ---------------------------------------------------------------------------
// Softmax stats (unchanged from fp32 baseline)
// ---------------------------------------------------------------------------
__global__ __launch_bounds__(256) void k_rowstats(const float* __restrict__ aff,
                                                  const int* __restrict__ qmask,
                                                  float* __restrict__ rowmax,
                                                  float* __restrict__ rowsum) {
  int row = blockIdx.x * 4 + (threadIdx.x >> 6);
  int lane = threadIdx.x & 63;
  int b = row >> 10;
  const float* r = aff + (size_t)row * Q_;
  const int* qm = qmask + b * Q_;
  int q0 = lane * 4;
  float4 x = *(const float4*)(r + q0);
  float4 y = *(const float4*)(r + q0 + 256);
  int4 ma = *(const int4*)(qm + q0);
  int4 mb = *(const int4*)(qm + q0 + 256);
  float v[8];
  v[0] = ma.x ? HUGE_NEG : x.x;
  v[1] = ma.y ? HUGE_NEG : x.y;
  v[2] = ma.z ? HUGE_NEG : x.z;
  v[3] = ma.w ? HUGE_NEG : x.w;
  v[4] = mb.x ? HUGE_NEG : y.x;
  v[5] = mb.y ? HUGE_NEG : y.y;
  v[6] = mb.z ? HUGE_NEG : y.z;
  v[7] = mb.w ? HUGE_NEG : y.w;
  float m = v[0];
#pragma unroll
  for (int j = 1; j < 8; ++j) m = fmaxf(m, v[j]);
#pragma unroll
  for (int off = 32; off > 0; off >>= 1) m = fmaxf(m, __shfl_xor(m, off));
  float s = 0.f;
#pragma unroll
  for (int j = 0; j < 8; ++j) s += __expf(v[j] - m);
#pragma unroll
  for (int off = 32; off > 0; off >>= 1) s += __shfl_xor(s, off);
  if (lane == 0) {
    rowmax[row] = m;
    rowsum[row] = s;
  }
}

__global__ __launch_bounds__(256) void k_colpart(const float* __restrict__ aff,
                                                 const int* __restrict__ pmask,
                                                 float* __restrict__ pmax_part,
                                                 float* __restrict__ psum_part) {
  int b = blockIdx.x;
  int q = blockIdx.y * 256 + threadIdx.x;
  int z = blockIdx.z;
  const float* ab = aff + ((size_t)b * P_ + z * 128) * Q_ + q;
  const int* pm = pmask + b * P_ + z * 128;
  float m = -INFINITY, s = 0.f;
  for (int p = 0; p < 128; ++p) {
    float v = pm[p] ? HUGE_NEG : ab[(size_t)p * Q_];
    float mn = fmaxf(m, v);
    s = s * __expf(m - mn) + __expf(v - mn);
    m = mn;
  }
  pmax_part[(b * 8 + z) * Q_ + q] = m;
  psum_part[(b * 8 + z) * Q_ + q] = s;
}

__global__ __launch_bounds__(256) void k_colmerge(
    const float* __restrict__ pmax_part, const float* __restrict__ psum_part,
    float* __restrict__ colmax, float* __restrict__ colsum) {
  int b = blockIdx.x;
  int q = blockIdx.y * 256 + threadIdx.x;
  float m = -INFINITY;
#pragma unroll
  for (int z = 0; z < 8; ++z) m = fmaxf(m, pmax_part[(b * 8 + z) * Q_ + q]);
  float s = 0.f;
#pragma unroll
  for (int z = 0; z < 8; ++z)
    s += psum_part[(b * 8 + z) * Q_ + q] *
         __expf(pmax_part[(b * 8 + z) * Q_ + q] - m);
  colmax[b * Q_ + q] = m;
  colsum[b * Q_ + q] = s;
}

// ---------------------------------------------------------------------------
// K1: qp[b][q][pd] = sum_d q[q][d] * W[pd][d], hi/lo split inputs, 3 MFMAs.
// Epilogue: write qp_hi / qp_lo bf16. grid = (PD/128, Q/128, B)
// ---------------------------------------------------------------------------
__global__ __launch_bounds__(256) void k1_proj(
    const unsigned short* __restrict__ qh, const unsigned short* __restrict__ ql,
    const unsigned short* __restrict__ Wh, const unsigned short* __restrict__ Wl,
    unsigned short* __restrict__ qph, unsigned short* __restrict__ qpl) {
  __shared__ alignas(16) unsigned short Ah[128 * 32];
  __shared__ alignas(16) unsigned short Al[128 * 32];
  __shared__ alignas(16) unsigned short Bh[128 * 32];
  __shared__ alignas(16) unsigned short Bl[128 * 32];
  int j0 = blockIdx.x * 128, i0 = blockIdx.y * 128, b = blockIdx.z;
  int tid = threadIdx.x, w = tid >> 6, l = tid & 63;
  int wr = w >> 1, wc = w & 1;
  const unsigned short* qhb = qh + (size_t)b * Q_ * QD_;
  const unsigned short* qlb = ql + (size_t)b * Q_ * QD_;
  f32x4 acc[4][4];
#pragma unroll
  for (int m = 0; m < 4; ++m)
#pragma unroll
    for (int n = 0; n < 4; ++n) acc[m][n] = (f32x4){0.f, 0.f, 0.f, 0.f};

  int r0 = w * 32 + (l >> 2);
  int s8 = (l & 3) * 8;
  int fr = l & 15, fs = (l >> 4) * 8;

  for (int k0 = 0; k0 < QD_; k0 += 32) {
    const unsigned short* gA = qhb + (size_t)(i0 + r0) * QD_ + k0 + s8;
    dma16(gA, Ah + (w * 32) * 32);
    dma16(gA + 16 * QD_, Ah + (w * 32 + 16) * 32);
    const unsigned short* gA2 = qlb + (size_t)(i0 + r0) * QD_ + k0 + s8;
    dma16(gA2, Al + (w * 32) * 32);
    dma16(gA2 + 16 * QD_, Al + (w * 32 + 16) * 32);
    const unsigned short* gB = Wh + (size_t)(j0 + r0) * QD_ + k0 + s8;
    dma16(gB, Bh + (w * 32) * 32);
    dma16(gB + 16 * QD_, Bh + (w * 32 + 16) * 32);
    const unsigned short* gB2 = Wl + (size_t)(j0 + r0) * QD_ + k0 + s8;
    dma16(gB2, Bl + (w * 32) * 32);
    dma16(gB2 + 16 * QD_, Bl + (w * 32 + 16) * 32);
    __syncthreads();

    bf16x8 ah[4], al[4];
#pragma unroll
    for (int m = 0; m < 4; ++m) {
      ah[m] = *(const bf16x8*)(Ah + (wr * 64 + m * 16 + fr) * 32 + fs);
      al[m] = *(const bf16x8*)(Al + (wr * 64 + m * 16 + fr) * 32 + fs);
    }
#pragma unroll
    for (int n = 0; n < 4; ++n) {
      bf16x8 bh = *(const bf16x8*)(Bh + (wc * 64 + n * 16 + fr) * 32 + fs);
      bf16x8 bl = *(const bf16x8*)(Bl + (wc * 64 + n * 16 + fr) * 32 + fs);
#pragma unroll
      for (int m = 0; m < 4; ++m) {
        acc[m][n] = __builtin_amdgcn_mfma_f32_16x16x32_bf16(ah[m], bh, acc[m][n], 0, 0, 0);
        acc[m][n] = __builtin_amdgcn_mfma_f32_16x16x32_bf16(ah[m], bl, acc[m][n], 0, 0, 0);
        acc[m][n] = __builtin_amdgcn_mfma_f32_16x16x32_bf16(al[m], bh, acc[m][n], 0, 0, 0);
      }
    }
    __syncthreads();
  }

  size_t base = (size_t)b * Q_ * PD_;
  int fq = l >> 4;
#pragma unroll
  for (int m = 0; m < 4; ++m) {
    int row = i0 + wr * 64 + m * 16 + fq * 4;
#pragma unroll
    for (int n = 0; n < 4; ++n) {
      int col = j0 + wc * 64 + n * 16 + fr;
#pragma unroll
      for (int r = 0; r < 4; ++r) {
        float v = acc[m][n][r];
        unsigned short h = f2bf(v);
        qph[base + (size_t)(row + r) * PD_ + col] = h;
        qpl[base + (size_t)(row + r) * PD_ + col] = f2bf(v - bf2f(h));
      }
    }
  }
}

// ---------------------------------------------------------------------------
// K2: aff[b][p][q] = sum_d p[p][d] * qp[q][d], split x split, 3 MFMAs.
// A reg-staged (split on the fly from fp32 p), B DMA. grid = (Q/128, P/128, B)
// ---------------------------------------------------------------------------
__global__ __launch_bounds__(256) void k2_aff(
    const float* __restrict__ pmat, const unsigned short* __restrict__ qph,
    const unsigned short* __restrict__ qpl, float* __restrict__ aff) {
  __shared__ alignas(16) unsigned short Ah[128 * 32];
  __shared__ alignas(16) unsigned short Al[128 * 32];
  __shared__ alignas(16) unsigned short Bh[128 * 32];
  __shared__ alignas(16) unsigned short Bl[128 * 32];
  int j0 = blockIdx.x * 128, i0 = blockIdx.y * 128, b = blockIdx.z;
  int tid = threadIdx.x, w = tid >> 6, l = tid & 63;
  int wr = w >> 1, wc = w & 1;
  const float* pb = pmat + (size_t)b * P_ * PD_;
  const unsigned short* Bhb = qph + (size_t)b * Q_ * PD_;
  const unsigned short* Blb = qpl + (size_t)b * Q_ * PD_;
  f32x4 acc[4][4];
#pragma unroll
  for (int m = 0; m < 4; ++m)
#pragma unroll
    for (int n = 0; n < 4; ++n) acc[m][n] = (f32x4){0.f, 0.f, 0.f, 0.f};

  int r0 = w * 32 + (l >> 2);
  int s8 = (l & 3) * 8;
  int fr = l & 15, fs = (l >> 4) * 8;

  for (int k0 = 0; k0 < PD_; k0 += 32) {
#pragma unroll
    for (int pass = 0; pass < 2; ++pass) {
      int idx = tid + pass * 256;
      int row = idx >> 2;
      int ch = (idx & 3) * 8;
      const float* src = pb + (size_t)(i0 + row) * PD_ + k0 + ch;
      float4 v0 = *(const float4*)src;
      float4 v1 = *(const float4*)(src + 4);
      float vv[8] = {v0.x, v0.y, v0.z, v0.w, v1.x, v1.y, v1.z, v1.w};
      us8 hv, lv;
#pragma unroll
      for (int j = 0; j < 8; ++j) {
        unsigned short h = f2bf(vv[j]);
        hv[j] = h;
        lv[j] = f2bf(vv[j] - bf2f(h));
      }
      *(us8*)(Ah + row * 32 + ch) = hv;
      *(us8*)(Al + row * 32 + ch) = lv;
    }
    const unsigned short* gB = Bhb + (size_t)(j0 + r0) * PD_ + k0 + s8;
    dma16(gB, Bh + (w * 32) * 32);
    dma16(gB + 16 * PD_, Bh + (w * 32 + 16) * 32);
    const unsigned short* gB2 = Blb + (size_t)(j0 + r0) * PD_ + k0 + s8;
    dma16(gB2, Bl + (w * 32) * 32);
    dma16(gB2 + 16 * PD_, Bl + (w * 32 + 16) * 32);
    __syncthreads();

    bf16x8 ah[4], al[4];
#pragma unroll
    for (int m = 0; m < 4; ++m) {
      ah[m] = *(const bf16x8*)(Ah + (wr * 64 + m * 16 + fr) * 32 + fs);
      al[m] = *(const bf16x8*)(Al + (wr * 64 + m * 16 + fr) * 32 + fs);
    }
#pragma unroll
    for (int n = 0; n < 4; ++n) {
      bf16x8 bh = *(const bf16x8*)(Bh + (wc * 64 + n * 16 + fr) * 32 + fs);
      bf16x8 bl = *(const bf16x8*)(Bl + (wc * 64 + n * 16 + fr) * 32 + fs);
#pragma unroll
      for (int m = 0; m < 4; ++m) {
        acc[m][n] = __builtin_amdgcn_mfma_f32_16x16x32_bf16(ah[m], bh, acc[m][n], 0, 0, 0);
        acc[m][n] = __builtin_amdgcn_mfma_f32_16x16x32_bf16(ah[m], bl, acc[m][n], 0, 0, 0);
        acc[m][n] = __builtin_amdgcn_mfma_f32_16x16x32_bf16(al[m], bh, acc[m][n], 0, 0, 0);
      }
    }
    __syncthreads();
  }

  float* Cb = aff + (size_t)b * P_ * Q_;
  int fq = l >> 4;
#pragma unroll
  for (int m = 0; m < 4; ++m) {
    int row = i0 + wr * 64 + m * 16 + fq * 4;
#pragma unroll
    for (int n = 0; n < 4; ++n) {
      int col = j0 + wc * 64 + n * 16 + fr;
#pragma unroll
      for (int r = 0; r < 4; ++r)
        Cb[(size_t)(row + r) * Q_ + col] = acc[m][n][r];
    }
  }
}

// ---------------------------------------------------------------------------
// K4: out2[b][q][d] = (sum_p WQ[q][p] * pT[d][p]) / colsum[q]
// Both operands DMA. grid = (PD/128, Q/128, B)
// ---------------------------------------------------------------------------
__global__ __launch_bounds__(256) void k4_attn(
    const unsigned short* __restrict__ WQ, const unsigned short* __restrict__ pT,
    const float* __restrict__ colsum, float* __restrict__ out2) {
  __shared__ alignas(16) unsigned short As[128 * 32];
  __shared__ alignas(16) unsigned short Bs[128 * 32];
  __shared__ float cinv[128];
  int j0 = blockIdx.x * 128, i0 = blockIdx.y * 128, b = blockIdx.z;
  int tid = threadIdx.x, w = tid >> 6, l = tid & 63;
  int wr = w >> 1, wc = w & 1;
  if (tid < 128) cinv[tid] = 1.0f / colsum[b * Q_ + i0 + tid];
  const unsigned short* Ab = WQ + (size_t)b * Q_ * P_;
  const unsigned short* Bb = pT + (size_t)b * PD_ * P_;
  f32x4 acc[4][4];
#pragma unroll
  for (int m = 0; m < 4; ++m)
#pragma unroll
    for (int n = 0; n < 4; ++n) acc[m][n] = (f32x4){0.f, 0.f, 0.f, 0.f};

  int r0 = w * 32 + (l >> 2);
  int s8 = (l & 3) * 8;
  int fr = l & 15, fs = (l >> 4) * 8;

  for (int k0 = 0; k0 < P_; k0 += 32) {
    const unsigned short* gA = Ab + (size_t)(i0 + r0) * P_ + k0 + s8;
    dma16(gA, As + (w * 32) * 32);
    dma16(gA + 16 * P_, As + (w * 32 + 16) * 32);
    const unsigned short* gB = Bb + (size_t)(j0 + r0) * P_ + k0 + s8;
    dma16(gB, Bs + (w * 32) * 32);
    dma16(gB + 16 * P_, Bs + (w * 32 + 16) * 32);
    __syncthreads();

    bf16x8 a[4], bb[4];
#pragma unroll
    for (int m = 0; m < 4; ++m)
      a[m] = *(const bf16x8*)(As + (wr * 64 + m * 16 + fr) * 32 + fs);
#pragma unroll
    for (int n = 0; n < 4; ++n)
      bb[n] = *(const bf16x8*)(Bs + (wc * 64 + n * 16 + fr) * 32 + fs);
#pragma unroll
    for (int m = 0; m < 4; ++m)
#pragma unroll
      for (int n = 0; n < 4; ++n)
        acc[m][n] = __builtin_amdgcn_mfma_f32_16x16x32_bf16(a[m], bb[n], acc[m][n], 0, 0, 0);
    __syncthreads();
  }

  float* Cb = out2 + (size_t)b * Q_ * PD_;
  int fq = l >> 4;
#pragma unroll
  for (int m = 0; m < 4; ++m) {
    int rl = wr * 64 + m * 16 + fq * 4;
#pragma unroll
    for (int n = 0; n < 4; ++n) {
      int col = j0 + wc * 64 + n * 16 + fr;
#pragma unroll
      for (int r = 0; r < 4; ++r)
        Cb[(size_t)(i0 + rl + r) * PD_ + col] = acc[m][n][r] * cinv[rl + r];
    }
  }
}

// ---------------------------------------------------------------------------
// K5: out1[b][p][c] = (sum_q exp(aff'[p][q]-rowmax[p]) * candT[c][q]) / rowsum[p]
// A reg-staged (exp on the fly), B DMA. grid = (CD/128, P/128, B)
// ---------------------------------------------------------------------------
__global__ __launch_bounds__(256) void k5_attn(
    const float* __restrict__ aff, const unsigned short* __restrict__ candT,
    const int* __restrict__ qmask, const float* __restrict__ rowmax,
    const float* __restrict__ rowsum, float* __restrict__ out1) {
  __shared__ alignas(16) unsigned short As[128 * 32];
  __shared__ alignas(16) unsigned short Bs[128 * 32];
  __shared__ float rmx[128], rinv[128];
  int j0 = blockIdx.x * 128, i0 = blockIdx.y * 128, b = blockIdx.z;
  int tid = threadIdx.x, w = tid >> 6, l = tid & 63;
  int wr = w >> 1, wc = w & 1;
  if (tid < 128) {
    rmx[tid] = rowmax[b * P_ + i0 + tid];
    rinv[tid] = 1.0f / rowsum[b * P_ + i0 + tid];
  }
  __syncthreads();
  const float* affb = aff + (size_t)b * P_ * Q_;
  const unsigned short* Bb = candT + (size_t)b * CD_ * Q_;
  const int* qmb = qmask + b * Q_;
  f32x4 acc[4][4];
#pragma unroll
  for (int m = 0; m < 4; ++m)
#pragma unroll
    for (int n = 0; n < 4; ++n) acc[m][n] = (f32x4){0.f, 0.f, 0.f, 0.f};

  int r0 = w * 32 + (l >> 2);
  int s8 = (l & 3) * 8;
  int fr = l & 15, fs = (l >> 4) * 8;

  for (int k0 = 0; k0 < Q_; k0 += 32) {
#pragma unroll
    for (int pass = 0; pass < 2; ++pass) {
      int idx = tid + pass * 256;
      int row = idx >> 2;
      int ch = (idx & 3) * 8;
      const float* src = affb + (size_t)(i0 + row) * Q_ + k0 + ch;
      float4 v0 = *(const float4*)src;
      float4 v1 = *(const float4*)(src + 4);
      int4 m0 = *(const int4*)(qmb + k0 + ch);
      int4 m1 = *(const int4*)(qmb + k0 + ch + 4);
      float rm = rmx[row];
      float vv[8] = {v0.x, v0.y, v0.z, v0.w, v1.x, v1.y, v1.z, v1.w};
      int mm[8] = {m0.x, m0.y, m0.z, m0.w, m1.x, m1.y, m1.z, m1.w};
      us8 e;
#pragma unroll
      for (int j = 0; j < 8; ++j)
        e[j] = f2bf(__expf((mm[j] ? HUGE_NEG : vv[j]) - rm));
      *(us8*)(As + row * 32 + ch) = e;
    }
    const unsigned short* gB = Bb + (size_t)(j0 + r0) * Q_ + k0 + s8;
    dma16(gB, Bs + (w * 32) * 32);
    dma16(gB + 16 * Q_, Bs + (w * 32 + 16) * 32);
    __syncthreads();

    bf16x8 a[4], bb[4];
#pragma unroll
    for (int m = 0; m < 4; ++m)
      a[m] = *(const bf16x8*)(As + (wr * 64 + m * 16 + fr) * 32 + fs);
#pragma unroll
    for (int n = 0; n < 4; ++n)
      bb[n] = *(const bf16x8*)(Bs + (wc * 64 + n * 16 + fr) * 32 + fs);
#pragma unroll
    for (int m = 0; m < 4; ++m)
#pragma unroll
      for (int n = 0; n < 4; ++n)
        acc[m][n] = __builtin_amdgcn_mfma_f32_16x16x32_bf16(a[m], bb[n], acc[m][n], 0, 0, 0);
    __syncthreads();
  }

  float* Cb = out1 + (size_t)b * P_ * CD_;
  int fq = l >> 4;
#pragma unroll
  for (int m = 0; m < 4; ++m) {
    int rl = wr * 64 + m * 16 + fq * 4;
#pragma unroll
    for (int n = 0; n < 4; ++n) {
      int col = j0 + wc * 64 + n * 16 + fr;
#pragma unroll
      for (int r = 0; r < 4; ++r)
        Cb[(size_t)(i0 + rl + r) * CD_ + col] = acc[m][n][r] * rinv[rl + r];
    }
  }
}

// ---------------------------------------------------------------------------
extern "C" void kernel_launch(void* const* d_in, const int* in_sizes, int n_in,
                              void* d_out, int out_size, void* d_ws,
                              size_t ws_size, hipStream_t stream) {
  const float* p = (const float*)d_in[0];
  const float* q = (const float*)d_in[1];
  const int* pmask = (const int*)d_in[2];
  const int* qmask = (const int*)d_in[3];
  const float* W = (const float*)d_in[4];
  float* out = (float*)d_out;

  char* ws = (char*)d_ws;
  size_t off = 0;
  auto alloc = [&](size_t bytes) {
    void* r = ws + off;
    off += (bytes + 255) & ~(size_t)255;
    return r;
  };
  // contiguous (qh, ql) pair -> reused as candT [B][CD][Q] bf16 after K1
  unsigned short* qh = (unsigned short*)alloc((size_t)B_ * Q_ * QD_ * 2);
  unsigned short* ql = (unsigned short*)alloc((size_t)B_ * Q_ * QD_ * 2);
  unsigned short* candT = qh;
  unsigned short* Wh = (unsigned short*)alloc((size_t)PD_ * QD_ * 2);
  unsigned short* Wl = (unsigned short*)alloc((size_t)PD_ * QD_ * 2);
  // contiguous (qph, qpl) pair -> reused as pT [B][PD][P] bf16 after K2
  unsigned short* qph = (unsigned short*)alloc((size_t)B_ * Q_ * PD_ * 2);
  unsigned short* qpl = (unsigned short*)alloc((size_t)B_ * Q_ * PD_ * 2);
  unsigned short* pT = qph;
  float* aff = (float*)alloc((size_t)B_ * P_ * Q_ * 4);
  unsigned short* WQ = (unsigned short*)alloc((size_t)B_ * Q_ * P_ * 2);
  float* rowmax = (float*)alloc((size_t)B_ * P_ * 4);
  float* rowsum = (float*)alloc((size_t)B_ * P_ * 4);
  float* colmax = (float*)alloc((size_t)B_ * Q_ * 4);
  float* colsum = (float*)alloc((size_t)B_ * Q_ * 4);
  float* pmax_part = (float*)alloc((size_t)B_ * 8 * Q_ * 4);
  float* psum_part = (float*)alloc((size_t)B_ * 8 * Q_ * 4);

  float* out1 = out;                          // [B,P,1536]
  float* out2 = out + (size_t)B_ * P_ * CD_;  // [B,Q,768]

  // 1. splits
  {
    int n4 = B_ * Q_ * QD_ / 4;
    k_split<<<(n4 + 255) / 256, 256, 0, stream>>>(q, qh, ql, n4);
    int n4w = PD_ * QD_ / 4;
    k_split<<<(n4w + 255) / 256, 256, 0, stream>>>(W, Wh, Wl, n4w);
  }
  // 2. K1 projection
  k1_proj<<<dim3(PD_ / 128, Q_ / 128, B_), 256, 0, stream>>>(qh, ql, Wh, Wl,
                                                             qph, qpl);
  // 3. K2 affinity
  k2_aff<<<dim3(Q_ / 128, P_ / 128, B_), 256, 0, stream>>>(p, qph, qpl, aff);
  // 4. softmax stats
  k_rowstats<<<B_ * P_ / 4, 256, 0, stream>>>(aff, qmask, rowmax, rowsum);
  k_colpart<<<dim3(B_, Q_ / 256, 8), 256, 0, stream>>>(aff, pmask, pmax_part,
                                                       psum_part);
  k_colmerge<<<dim3(B_, Q_ / 256), 256, 0, stream>>>(pmax_part, psum_part,
                                                     colmax, colsum);
  // 5. WQ = transposed exp weights
  k_wq<<<dim3(P_ / 64, Q_ / 64, B_), 256, 0, stream>>>(aff, pmask, colmax, WQ);
  // 6. pT = p transposed bf16 (into dead qp region)
  k_t2b<<<dim3(P_ / 64, PD_ / 64, B_), 256, 0, stream>>>(
      p, pT, P_, PD_, (size_t)PD_ * P_, 0);
  // 7. K4 -> out2
  k4_attn<<<dim3(PD_ / 128, Q_ / 128, B_), 256, 0, stream>>>(WQ, pT, colsum,
                                                             out2);
  // 8. candT (into dead qh/ql region): cols 0..767 from q, 768..1535 from out2
  k_t2b<<<dim3(Q_ / 64, QD_ / 64, B_), 256, 0, stream>>>(
      q, candT, Q_, QD_, (size_t)CD_ * Q_, 0);
  k_t2b<<<dim3(Q_ / 64, PD_ / 64, B_), 256, 0, stream>>>(
      out2, candT, Q_, PD_, (size_t)CD_ * Q_, QD_);
  // 9. K5 -> out1
  k5_attn<<<dim3(CD_ / 128, P_ / 128, B_), 256, 0, stream>>>(
      aff, candT, qmask, rowmax, rowsum, out1);
}

// Round 3
// 205.468 us; speedup vs baseline: 3.7839x; 1.3547x over previous
//
#include <hip/hip_runtime.h>
#include <math.h>

// Problem constants
constexpr int B_  = 16;
constexpr int P_  = 1024;
constexpr int Q_  = 512;
constexpr int PD_ = 768;   // p_dim
constexpr int QD_ = 768;   // q_dim
constexpr int CD_ = 1536;  // q_dim + p_dim

#define HUGE_NEG (-1e8f)

typedef __attribute__((ext_vector_type(8))) _Float16 f16x8;
typedef __attribute__((ext_vector_type(4))) _Float16 f16x4;
typedef __attribute__((ext_vector_type(4))) float f32x4;

// async global->LDS DMA, 16B/lane: HW writes lds_base + lane*16 (wave-linear).
__device__ __forceinline__ void dma16(const void* g, void* l) {
  __builtin_amdgcn_global_load_lds((__attribute__((address_space(1))) void*)g,
                                   (__attribute__((address_space(3))) void*)l,
                                   16, 0, 0);
}

// ---------------------------------------------------------------------------
// fp32 -> fp16 convert, 8 elems/thread.
// ---------------------------------------------------------------------------
__global__ __launch_bounds__(256) void k_cvt(const float* __restrict__ src,
                                             _Float16* __restrict__ dst, int n8) {
  int i = blockIdx.x * 256 + threadIdx.x;
  if (i >= n8) return;
  float4 a = ((const float4*)src)[2 * i];
  float4 b = ((const float4*)src)[2 * i + 1];
  f16x8 o = {(_Float16)a.x, (_Float16)a.y, (_Float16)a.z, (_Float16)a.w,
             (_Float16)b.x, (_Float16)b.y, (_Float16)b.z, (_Float16)b.w};
  ((f16x8*)dst)[i] = o;
}

// ---------------------------------------------------------------------------
// Transpose fp32 [b][R][C] -> fp16 dst[b][C][R] (row stride R, col offset).
// 64x64 tiles. grid = (R/64, C/64, B)
// ---------------------------------------------------------------------------
__global__ __launch_bounds__(256) void k_t2b16(const float* __restrict__ src,
                                               _Float16* __restrict__ dst,
                                               int R, int C, size_t dstBatch,
                                               int colOff) {
  __shared__ _Float16 T[64][72];
  int r0 = blockIdx.x * 64, c0 = blockIdx.y * 64, b = blockIdx.z;
  const float* S = src + (size_t)b * R * C;
  int tid = threadIdx.x;
  int rr = tid >> 4;
  int cc = (tid & 15) * 4;
#pragma unroll
  for (int k = 0; k < 4; ++k) {
    int r = rr + k * 16;
    float4 v = *(const float4*)(S + (size_t)(r0 + r) * C + c0 + cc);
    T[cc + 0][r] = (_Float16)v.x;
    T[cc + 1][r] = (_Float16)v.y;
    T[cc + 2][r] = (_Float16)v.z;
    T[cc + 3][r] = (_Float16)v.w;
  }
  __syncthreads();
  int cr = tid >> 2;
  int rc = (tid & 3) * 16;
  _Float16* D = dst + (size_t)b * dstBatch + (size_t)(colOff + c0 + cr) * R + r0;
  *(f16x8*)(D + rc) = *(f16x8*)&T[cr][rc];
  *(f16x8*)(D + rc + 8) = *(f16x8*)&T[cr][rc + 8];
}

// ---------------------------------------------------------------------------
// Row softmax fused: stats + WP[b][p][q] = fp16(exp(v - max)/sum)
// One wave per row. grid = B*P/4, block 256.
// ---------------------------------------------------------------------------
__global__ __launch_bounds__(256) void k_rowWP(const float* __restrict__ aff,
                                               const int* __restrict__ qmask,
                                               _Float16* __restrict__ WP) {
  int row = blockIdx.x * 4 + (threadIdx.x >> 6);
  int lane = threadIdx.x & 63;
  int b = row >> 10;  // P_ = 1024
  const float* r = aff + (size_t)row * Q_;
  const int* qm = qmask + b * Q_;
  int q0 = lane * 4;
  float4 x = *(const float4*)(r + q0);
  float4 y = *(const float4*)(r + q0 + 256);
  int4 ma = *(const int4*)(qm + q0);
  int4 mb = *(const int4*)(qm + q0 + 256);
  float v[8];
  v[0] = ma.x ? HUGE_NEG : x.x;
  v[1] = ma.y ? HUGE_NEG : x.y;
  v[2] = ma.z ? HUGE_NEG : x.z;
  v[3] = ma.w ? HUGE_NEG : x.w;
  v[4] = mb.x ? HUGE_NEG : y.x;
  v[5] = mb.y ? HUGE_NEG : y.y;
  v[6] = mb.z ? HUGE_NEG : y.z;
  v[7] = mb.w ? HUGE_NEG : y.w;
  float m = v[0];
#pragma unroll
  for (int j = 1; j < 8; ++j) m = fmaxf(m, v[j]);
#pragma unroll
  for (int off = 32; off > 0; off >>= 1) m = fmaxf(m, __shfl_xor(m, off));
  float s = 0.f;
#pragma unroll
  for (int j = 0; j < 8; ++j) s += __expf(v[j] - m);
#pragma unroll
  for (int off = 32; off > 0; off >>= 1) s += __shfl_xor(s, off);
  float inv = 1.0f / s;
  f16x4 w0, w1;
#pragma unroll
  for (int j = 0; j < 4; ++j) {
    w0[j] = (_Float16)(__expf(v[j] - m) * inv);
    w1[j] = (_Float16)(__expf(v[j + 4] - m) * inv);
  }
  _Float16* D = WP + (size_t)row * Q_;
  *(f16x4*)(D + q0) = w0;
  *(f16x4*)(D + q0 + 256) = w1;
}

// ---------------------------------------------------------------------------
// Column softmax partials + merge (over P per (b,q)).
// ---------------------------------------------------------------------------
__global__ __launch_bounds__(256) void k_colpart(const float* __restrict__ aff,
                                                 const int* __restrict__ pmask,
                                                 float* __restrict__ pmax_part,
                                                 float* __restrict__ psum_part) {
  int b = blockIdx.x;
  int q = blockIdx.y * 256 + threadIdx.x;
  int z = blockIdx.z;
  const float* ab = aff + ((size_t)b * P_ + z * 128) * Q_ + q;
  const int* pm = pmask + b * P_ + z * 128;
  float m = -INFINITY, s = 0.f;
  for (int p = 0; p < 128; ++p) {
    float v = pm[p] ? HUGE_NEG : ab[(size_t)p * Q_];
    float mn = fmaxf(m, v);
    s = s * __expf(m - mn) + __expf(v - mn);
    m = mn;
  }
  pmax_part[(b * 8 + z) * Q_ + q] = m;
  psum_part[(b * 8 + z) * Q_ + q] = s;
}

__global__ __launch_bounds__(256) void k_colmerge(
    const float* __restrict__ pmax_part, const float* __restrict__ psum_part,
    float* __restrict__ colmax, float* __restrict__ colsum) {
  int b = blockIdx.x;
  int q = blockIdx.y * 256 + threadIdx.x;
  float m = -INFINITY;
#pragma unroll
  for (int z = 0; z < 8; ++z) m = fmaxf(m, pmax_part[(b * 8 + z) * Q_ + q]);
  float s = 0.f;
#pragma unroll
  for (int z = 0; z < 8; ++z)
    s += psum_part[(b * 8 + z) * Q_ + q] *
         __expf(pmax_part[(b * 8 + z) * Q_ + q] - m);
  colmax[b * Q_ + q] = m;
  colsum[b * Q_ + q] = s;
}

// ---------------------------------------------------------------------------
// WQ[b][q][p] = fp16(exp((pmask?-HUGE:aff[p][q]) - colmax[q]) / colsum[q])
// grid = (P/64, Q/64, B)
// ---------------------------------------------------------------------------
__global__ __launch_bounds__(256) void k_wq16(const float* __restrict__ aff,
                                              const int* __restrict__ pmask,
                                              const float* __restrict__ colmax,
                                              const float* __restrict__ colsum,
                                              _Float16* __restrict__ WQ) {
  __shared__ _Float16 T[64][72];
  __shared__ float cmx[64], cinv[64];
  int p0 = blockIdx.x * 64, q0 = blockIdx.y * 64, b = blockIdx.z;
  int tid = threadIdx.x;
  if (tid < 64) {
    cmx[tid] = colmax[b * Q_ + q0 + tid];
    cinv[tid] = 1.0f / colsum[b * Q_ + q0 + tid];
  }
  __syncthreads();
  const float* A = aff + (size_t)b * P_ * Q_;
  const int* pm = pmask + b * P_;
  int rr = tid >> 4;
  int cc = (tid & 15) * 4;
#pragma unroll
  for (int k = 0; k < 4; ++k) {
    int r = rr + k * 16;
    int msk = pm[p0 + r];
    float4 v = *(const float4*)(A + (size_t)(p0 + r) * Q_ + q0 + cc);
    float vv[4] = {v.x, v.y, v.z, v.w};
#pragma unroll
    for (int j = 0; j < 4; ++j) {
      float e = __expf((msk ? HUGE_NEG : vv[j]) - cmx[cc + j]) * cinv[cc + j];
      T[cc + j][r] = (_Float16)e;
    }
  }
  __syncthreads();
  int cr = tid >> 2;
  int rc = (tid & 3) * 16;
  _Float16* D = WQ + ((size_t)b * Q_ + q0 + cr) * P_ + p0;
  *(f16x8*)(D + rc) = *(f16x8*)&T[cr][rc];
  *(f16x8*)(D + rc + 8) = *(f16x8*)&T[cr][rc + 8];
}

// ---------------------------------------------------------------------------
// Common fp16 GEMM core: 128x128 tile, 4 waves, BK=32, pure DMA staging,
// C = A(rows i, k-contig, LDA) * B(rows j, k-contig, LDB)^T, fp32 acc.
// ---------------------------------------------------------------------------
template <int K, int LDA, int LDB>
__device__ __forceinline__ void gemm_f16(const _Float16* __restrict__ Ab,
                                         const _Float16* __restrict__ Bb,
                                         _Float16* As, _Float16* Bs,
                                         f32x4 (&acc)[4][4], int w, int l) {
  int r0 = w * 32 + (l >> 2);
  int s8 = (l & 3) * 8;
  int fr = l & 15, fs = (l >> 4) * 8;
  int wr = w >> 1, wc = w & 1;
  for (int k0 = 0; k0 < K; k0 += 32) {
    dma16(Ab + (size_t)r0 * LDA + k0 + s8, As + (w * 32) * 32);
    dma16(Ab + (size_t)(r0 + 16) * LDA + k0 + s8, As + (w * 32 + 16) * 32);
    dma16(Bb + (size_t)r0 * LDB + k0 + s8, Bs + (w * 32) * 32);
    dma16(Bb + (size_t)(r0 + 16) * LDB + k0 + s8, Bs + (w * 32 + 16) * 32);
    __syncthreads();
    f16x8 a[4];
#pragma unroll
    for (int m = 0; m < 4; ++m)
      a[m] = *(const f16x8*)(As + (wr * 64 + m * 16 + fr) * 32 + fs);
#pragma unroll
    for (int n = 0; n < 4; ++n) {
      f16x8 bn = *(const f16x8*)(Bs + (wc * 64 + n * 16 + fr) * 32 + fs);
#pragma unroll
      for (int m = 0; m < 4; ++m)
        acc[m][n] =
            __builtin_amdgcn_mfma_f32_16x16x32_f16(a[m], bn, acc[m][n], 0, 0, 0);
    }
    __syncthreads();
  }
}

// bijective XCD swizzle (nwg % 8 == 0)
#define SWZ_DECODE(GX, GY)                                          \
  int lin = blockIdx.x + (GX) * (blockIdx.y + (GY) * blockIdx.z);   \
  constexpr int NWG = (GX) * (GY) * B_;                             \
  int w8 = (lin & 7) * (NWG / 8) + (lin >> 3);                      \
  int j0 = (w8 % (GX)) * 128;                                       \
  int t_ = w8 / (GX);                                               \
  int i0 = (t_ % (GY)) * 128;                                       \
  int b = t_ / (GY);

// ---------------------------------------------------------------------------
// K1: qp[b][q][pd] = sum_d q16[q][d] * W16[pd][d]. grid (PD/128, Q/128, B)
// ---------------------------------------------------------------------------
__global__ __launch_bounds__(256) void k1_proj(const _Float16* __restrict__ q16,
                                               const _Float16* __restrict__ W16,
                                               _Float16* __restrict__ qp) {
  __shared__ alignas(16) _Float16 As[128 * 32];
  __shared__ alignas(16) _Float16 Bs[128 * 32];
  SWZ_DECODE(PD_ / 128, Q_ / 128)
  int tid = threadIdx.x, w = tid >> 6, l = tid & 63;
  f32x4 acc[4][4];
#pragma unroll
  for (int m = 0; m < 4; ++m)
#pragma unroll
    for (int n = 0; n < 4; ++n) acc[m][n] = (f32x4){0.f, 0.f, 0.f, 0.f};
  gemm_f16<QD_, QD_, QD_>(q16 + (size_t)b * Q_ * QD_ + (size_t)i0 * QD_,
                          W16 + (size_t)j0 * QD_, As, Bs, acc, w, l);
  int wr = w >> 1, wc = w & 1, fr = l & 15, fq = l >> 4;
  _Float16* O = qp + (size_t)b * Q_ * PD_;
#pragma unroll
  for (int m = 0; m < 4; ++m) {
    int rl = wr * 64 + m * 16 + fq * 4;
#pragma unroll
    for (int n = 0; n < 4; ++n) {
      int cl = wc * 64 + n * 16 + fr;
#pragma unroll
      for (int r = 0; r < 4; ++r)
        O[(size_t)(i0 + rl + r) * PD_ + j0 + cl] = (_Float16)acc[m][n][r];
    }
  }
}

// ---------------------------------------------------------------------------
// K2: aff[b][p][q] = sum_d p16[p][d] * qp[q][d]. grid (Q/128, P/128, B)
// ---------------------------------------------------------------------------
__global__ __launch_bounds__(256) void k2_aff(const _Float16* __restrict__ p16,
                                              const _Float16* __restrict__ qp,
                                              float* __restrict__ aff) {
  __shared__ alignas(16) _Float16 As[128 * 32];
  __shared__ alignas(16) _Float16 Bs[128 * 32];
  SWZ_DECODE(Q_ / 128, P_ / 128)
  int tid = threadIdx.x, w = tid >> 6, l = tid & 63;
  f32x4 acc[4][4];
#pragma unroll
  for (int m = 0; m < 4; ++m)
#pragma unroll
    for (int n = 0; n < 4; ++n) acc[m][n] = (f32x4){0.f, 0.f, 0.f, 0.f};
  gemm_f16<PD_, PD_, PD_>(p16 + (size_t)b * P_ * PD_ + (size_t)i0 * PD_,
                          qp + (size_t)b * Q_ * PD_ + (size_t)j0 * PD_, As, Bs,
                          acc, w, l);
  int wr = w >> 1, wc = w & 1, fr = l & 15, fq = l >> 4;
  float* Cb = aff + (size_t)b * P_ * Q_;
#pragma unroll
  for (int m = 0; m < 4; ++m) {
    int rl = wr * 64 + m * 16 + fq * 4;
#pragma unroll
    for (int n = 0; n < 4; ++n) {
      int cl = wc * 64 + n * 16 + fr;
#pragma unroll
      for (int r = 0; r < 4; ++r)
        Cb[(size_t)(i0 + rl + r) * Q_ + j0 + cl] = acc[m][n][r];
    }
  }
}

// ---------------------------------------------------------------------------
// K4: out2[b][q][d] = sum_p WQ[q][p] * pT[d][p]  (cinv pre-folded into WQ)
// Also writes candT[b][768+d][q] fp16. grid (PD/128, Q/128, B)
// ---------------------------------------------------------------------------
__global__ __launch_bounds__(256) void k4_attn(const _Float16* __restrict__ WQ,
                                               const _Float16* __restrict__ pT,
                                               float* __restrict__ out2,
                                               _Float16* __restrict__ candT) {
  __shared__ alignas(16) _Float16 As[128 * 32];
  __shared__ alignas(16) _Float16 Bs[128 * 32];
  SWZ_DECODE(PD_ / 128, Q_ / 128)
  int tid = threadIdx.x, w = tid >> 6, l = tid & 63;
  f32x4 acc[4][4];
#pragma unroll
  for (int m = 0; m < 4; ++m)
#pragma unroll
    for (int n = 0; n < 4; ++n) acc[m][n] = (f32x4){0.f, 0.f, 0.f, 0.f};
  gemm_f16<P_, P_, P_>(WQ + (size_t)b * Q_ * P_ + (size_t)i0 * P_,
                       pT + (size_t)b * PD_ * P_ + (size_t)j0 * P_, As, Bs, acc,
                       w, l);
  int wr = w >> 1, wc = w & 1, fr = l & 15, fq = l >> 4;
  float* Cb = out2 + (size_t)b * Q_ * PD_;
  _Float16* Tb = candT + (size_t)b * CD_ * Q_;
#pragma unroll
  for (int m = 0; m < 4; ++m) {
    int rl = wr * 64 + m * 16 + fq * 4;
#pragma unroll
    for (int n = 0; n < 4; ++n) {
      int cl = wc * 64 + n * 16 + fr;
      f16x4 cv;
#pragma unroll
      for (int r = 0; r < 4; ++r) {
        float v = acc[m][n][r];
        Cb[(size_t)(i0 + rl + r) * PD_ + j0 + cl] = v;
        cv[r] = (_Float16)v;
      }
      *(f16x4*)(Tb + (size_t)(QD_ + j0 + cl) * Q_ + i0 + rl) = cv;
    }
  }
}

// ---------------------------------------------------------------------------
// K5: out1[b][p][c] = sum_q WP[p][q] * candT[c][q]  (rinv pre-folded into WP)
// grid (CD/128, P/128, B)
// ---------------------------------------------------------------------------
__global__ __launch_bounds__(256) void k5_attn(const _Float16* __restrict__ WP,
                                               const _Float16* __restrict__ candT,
                                               float* __restrict__ out1) {
  __shared__ alignas(16) _Float16 As[128 * 32];
  __shared__ alignas(16) _Float16 Bs[128 * 32];
  SWZ_DECODE(CD_ / 128, P_ / 128)
  int tid = threadIdx.x, w = tid >> 6, l = tid & 63;
  f32x4 acc[4][4];
#pragma unroll
  for (int m = 0; m < 4; ++m)
#pragma unroll
    for (int n = 0; n < 4; ++n) acc[m][n] = (f32x4){0.f, 0.f, 0.f, 0.f};
  gemm_f16<Q_, Q_, Q_>(WP + (size_t)b * P_ * Q_ + (size_t)i0 * Q_,
                       candT + (size_t)b * CD_ * Q_ + (size_t)j0 * Q_, As, Bs,
                       acc, w, l);
  int wr = w >> 1, wc = w & 1, fr = l & 15, fq = l >> 4;
  float* Cb = out1 + (size_t)b * P_ * CD_;
#pragma unroll
  for (int m = 0; m < 4; ++m) {
    int rl = wr * 64 + m * 16 + fq * 4;
#pragma unroll
    for (int n = 0; n < 4; ++n) {
      int cl = wc * 64 + n * 16 + fr;
#pragma unroll
      for (int r = 0; r < 4; ++r)
        Cb[(size_t)(i0 + rl + r) * CD_ + j0 + cl] = acc[m][n][r];
    }
  }
}

// ---------------------------------------------------------------------------
extern "C" void kernel_launch(void* const* d_in, const int* in_sizes, int n_in,
                              void* d_out, int out_size, void* d_ws,
                              size_t ws_size, hipStream_t stream) {
  const float* p = (const float*)d_in[0];
  const float* q = (const float*)d_in[1];
  const int* pmask = (const int*)d_in[2];
  const int* qmask = (const int*)d_in[3];
  const float* W = (const float*)d_in[4];
  float* out = (float*)d_out;

  char* ws = (char*)d_ws;
  size_t off = 0;
  auto alloc = [&](size_t bytes) {
    void* r = ws + off;
    off += (bytes + 255) & ~(size_t)255;
    return r;
  };
  // qh16 + qp16 contiguous -> reused as candT [B][CD][Q] fp16 (exact size)
  _Float16* qh16 = (_Float16*)alloc((size_t)B_ * Q_ * QD_ * 2);
  _Float16* qp16 = (_Float16*)alloc((size_t)B_ * Q_ * PD_ * 2);
  _Float16* candT = qh16;
  _Float16* Wh16 = (_Float16*)alloc((size_t)PD_ * QD_ * 2);
  _Float16* ph16 = (_Float16*)alloc((size_t)B_ * P_ * PD_ * 2);  // -> pT
  _Float16* pT = ph16;
  float* aff = (float*)alloc((size_t)B_ * P_ * Q_ * 4);
  _Float16* WP = (_Float16*)alloc((size_t)B_ * P_ * Q_ * 2);
  _Float16* WQ = (_Float16*)alloc((size_t)B_ * Q_ * P_ * 2);
  float* colmax = (float*)alloc((size_t)B_ * Q_ * 4);
  float* colsum = (float*)alloc((size_t)B_ * Q_ * 4);
  float* pmax_part = (float*)alloc((size_t)B_ * 8 * Q_ * 4);
  float* psum_part = (float*)alloc((size_t)B_ * 8 * Q_ * 4);

  float* out1 = out;                          // [B,P,1536]
  float* out2 = out + (size_t)B_ * P_ * CD_;  // [B,Q,768]

  // 1. fp16 conversions
  k_cvt<<<B_ * Q_ * QD_ / 8 / 256, 256, 0, stream>>>(q, qh16, B_ * Q_ * QD_ / 8);
  k_cvt<<<PD_ * QD_ / 8 / 256, 256, 0, stream>>>(W, Wh16, PD_ * QD_ / 8);
  k_cvt<<<B_ * P_ * PD_ / 8 / 256, 256, 0, stream>>>(p, ph16, B_ * P_ * PD_ / 8);
  // 2. K1 projection (fp16)
  k1_proj<<<dim3(PD_ / 128, Q_ / 128, B_), 256, 0, stream>>>(qh16, Wh16, qp16);
  // 3. K2 affinity (fp16 -> fp32 aff)
  k2_aff<<<dim3(Q_ / 128, P_ / 128, B_), 256, 0, stream>>>(ph16, qp16, aff);
  // 4. row softmax fused -> WP
  k_rowWP<<<B_ * P_ / 4, 256, 0, stream>>>(aff, qmask, WP);
  // 5. col softmax stats
  k_colpart<<<dim3(B_, Q_ / 256, 8), 256, 0, stream>>>(aff, pmask, pmax_part,
                                                       psum_part);
  k_colmerge<<<dim3(B_, Q_ / 256), 256, 0, stream>>>(pmax_part, psum_part,
                                                     colmax, colsum);
  // 6. WQ (exp + cinv fold, transposed, fp16)
  k_wq16<<<dim3(P_ / 64, Q_ / 64, B_), 256, 0, stream>>>(aff, pmask, colmax,
                                                         colsum, WQ);
  // 7. pT (fp32 p -> fp16 transposed; aliases ph16, dead after K2)
  k_t2b16<<<dim3(P_ / 64, PD_ / 64, B_), 256, 0, stream>>>(
      p, pT, P_, PD_, (size_t)PD_ * P_, 0);
  // 8. K4 -> out2 + candT upper half
  k4_attn<<<dim3(PD_ / 128, Q_ / 128, B_), 256, 0, stream>>>(WQ, pT, out2,
                                                             candT);
  // 9. candT lower half from q (aliases qh16/qp16, dead after K2)
  k_t2b16<<<dim3(Q_ / 64, QD_ / 64, B_), 256, 0, stream>>>(
      q, candT, Q_, QD_, (size_t)CD_ * Q_, 0);
  // 10. K5 -> out1
  k5_attn<<<dim3(CD_ / 128, P_ / 128, B_), 256, 0, stream>>>(WP, candT, out1);
}

// Round 4
// 169.162 us; speedup vs baseline: 4.5960x; 1.2146x over previous
//
#include <hip/hip_runtime.h>
#include <math.h>

// Problem constants
constexpr int B_  = 16;
constexpr int P_  = 1024;
constexpr int Q_  = 512;
constexpr int PD_ = 768;   // p_dim
constexpr int QD_ = 768;   // q_dim
constexpr int CD_ = 1536;  // q_dim + p_dim

#define HUGE_NEG (-1e8f)

typedef __attribute__((ext_vector_type(8))) _Float16 f16x8;
typedef __attribute__((ext_vector_type(4))) _Float16 f16x4;
typedef __attribute__((ext_vector_type(4))) float f32x4;

// async global->LDS DMA, 16B/lane: HW writes lds_base + lane*16 (wave-linear).
__device__ __forceinline__ void dma16(const void* g, void* l) {
  __builtin_amdgcn_global_load_lds((__attribute__((address_space(1))) void*)g,
                                   (__attribute__((address_space(3))) void*)l,
                                   16, 0, 0);
}

// ---------------------------------------------------------------------------
// fp32 -> fp16 convert, 8 elems/thread.
// ---------------------------------------------------------------------------
__global__ __launch_bounds__(256) void k_cvt(const float* __restrict__ src,
                                             _Float16* __restrict__ dst, int n8) {
  int i = blockIdx.x * 256 + threadIdx.x;
  if (i >= n8) return;
  float4 a = ((const float4*)src)[2 * i];
  float4 b = ((const float4*)src)[2 * i + 1];
  f16x8 o = {(_Float16)a.x, (_Float16)a.y, (_Float16)a.z, (_Float16)a.w,
             (_Float16)b.x, (_Float16)b.y, (_Float16)b.z, (_Float16)b.w};
  ((f16x8*)dst)[i] = o;
}

// ---------------------------------------------------------------------------
// Transpose fp32 [b][R][C] -> fp16 dst[b][C][R] (row stride R, col offset).
// 64x64 tiles. grid = (R/64, C/64, B)
// ---------------------------------------------------------------------------
__global__ __launch_bounds__(256) void k_t2b16(const float* __restrict__ src,
                                               _Float16* __restrict__ dst,
                                               int R, int C, size_t dstBatch,
                                               int colOff) {
  __shared__ _Float16 T[64][72];
  int r0 = blockIdx.x * 64, c0 = blockIdx.y * 64, b = blockIdx.z;
  const float* S = src + (size_t)b * R * C;
  int tid = threadIdx.x;
  int rr = tid >> 4;
  int cc = (tid & 15) * 4;
#pragma unroll
  for (int k = 0; k < 4; ++k) {
    int r = rr + k * 16;
    float4 v = *(const float4*)(S + (size_t)(r0 + r) * C + c0 + cc);
    T[cc + 0][r] = (_Float16)v.x;
    T[cc + 1][r] = (_Float16)v.y;
    T[cc + 2][r] = (_Float16)v.z;
    T[cc + 3][r] = (_Float16)v.w;
  }
  __syncthreads();
  int cr = tid >> 2;
  int rc = (tid & 3) * 16;
  _Float16* D = dst + (size_t)b * dstBatch + (size_t)(colOff + c0 + cr) * R + r0;
  *(f16x8*)(D + rc) = *(f16x8*)&T[cr][rc];
  *(f16x8*)(D + rc + 8) = *(f16x8*)&T[cr][rc + 8];
}

// ---------------------------------------------------------------------------
// Row softmax fused: stats + WP[b][p][q] = fp16(exp(v - max)/sum)
// One wave per row. grid = B*P/4, block 256.
// ---------------------------------------------------------------------------
__global__ __launch_bounds__(256) void k_rowWP(const float* __restrict__ aff,
                                               const int* __restrict__ qmask,
                                               _Float16* __restrict__ WP) {
  int row = blockIdx.x * 4 + (threadIdx.x >> 6);
  int lane = threadIdx.x & 63;
  int b = row >> 10;  // P_ = 1024
  const float* r = aff + (size_t)row * Q_;
  const int* qm = qmask + b * Q_;
  int q0 = lane * 4;
  float4 x = *(const float4*)(r + q0);
  float4 y = *(const float4*)(r + q0 + 256);
  int4 ma = *(const int4*)(qm + q0);
  int4 mb = *(const int4*)(qm + q0 + 256);
  float v[8];
  v[0] = ma.x ? HUGE_NEG : x.x;
  v[1] = ma.y ? HUGE_NEG : x.y;
  v[2] = ma.z ? HUGE_NEG : x.z;
  v[3] = ma.w ? HUGE_NEG : x.w;
  v[4] = mb.x ? HUGE_NEG : y.x;
  v[5] = mb.y ? HUGE_NEG : y.y;
  v[6] = mb.z ? HUGE_NEG : y.z;
  v[7] = mb.w ? HUGE_NEG : y.w;
  float m = v[0];
#pragma unroll
  for (int j = 1; j < 8; ++j) m = fmaxf(m, v[j]);
#pragma unroll
  for (int off = 32; off > 0; off >>= 1) m = fmaxf(m, __shfl_xor(m, off));
  float s = 0.f;
#pragma unroll
  for (int j = 0; j < 8; ++j) s += __expf(v[j] - m);
#pragma unroll
  for (int off = 32; off > 0; off >>= 1) s += __shfl_xor(s, off);
  float inv = 1.0f / s;
  f16x4 w0, w1;
#pragma unroll
  for (int j = 0; j < 4; ++j) {
    w0[j] = (_Float16)(__expf(v[j] - m) * inv);
    w1[j] = (_Float16)(__expf(v[j + 4] - m) * inv);
  }
  _Float16* D = WP + (size_t)row * Q_;
  *(f16x4*)(D + q0) = w0;
  *(f16x4*)(D + q0 + 256) = w1;
}

// ---------------------------------------------------------------------------
// Merge 8 column-stat partials. grid = (B, Q/256), block = 256.
// ---------------------------------------------------------------------------
__global__ __launch_bounds__(256) void k_colmerge(
    const float* __restrict__ pmax_part, const float* __restrict__ psum_part,
    float* __restrict__ colmax, float* __restrict__ colsum) {
  int b = blockIdx.x;
  int q = blockIdx.y * 256 + threadIdx.x;
  float m = -INFINITY;
#pragma unroll
  for (int z = 0; z < 8; ++z) m = fmaxf(m, pmax_part[(b * 8 + z) * Q_ + q]);
  float s = 0.f;
#pragma unroll
  for (int z = 0; z < 8; ++z)
    s += psum_part[(b * 8 + z) * Q_ + q] *
         __expf(pmax_part[(b * 8 + z) * Q_ + q] - m);
  colmax[b * Q_ + q] = m;
  colsum[b * Q_ + q] = s;
}

// ---------------------------------------------------------------------------
// WQ[b][q][p] = fp16(exp((pmask?-HUGE:aff[p][q]) - colmax[q]) / colsum[q])
// grid = (P/64, Q/64, B)
// ---------------------------------------------------------------------------
__global__ __launch_bounds__(256) void k_wq16(const float* __restrict__ aff,
                                              const int* __restrict__ pmask,
                                              const float* __restrict__ colmax,
                                              const float* __restrict__ colsum,
                                              _Float16* __restrict__ WQ) {
  __shared__ _Float16 T[64][72];
  __shared__ float cmx[64], cinv[64];
  int p0 = blockIdx.x * 64, q0 = blockIdx.y * 64, b = blockIdx.z;
  int tid = threadIdx.x;
  if (tid < 64) {
    cmx[tid] = colmax[b * Q_ + q0 + tid];
    cinv[tid] = 1.0f / colsum[b * Q_ + q0 + tid];
  }
  __syncthreads();
  const float* A = aff + (size_t)b * P_ * Q_;
  const int* pm = pmask + b * P_;
  int rr = tid >> 4;
  int cc = (tid & 15) * 4;
#pragma unroll
  for (int k = 0; k < 4; ++k) {
    int r = rr + k * 16;
    int msk = pm[p0 + r];
    float4 v = *(const float4*)(A + (size_t)(p0 + r) * Q_ + q0 + cc);
    float vv[4] = {v.x, v.y, v.z, v.w};
#pragma unroll
    for (int j = 0; j < 4; ++j) {
      float e = __expf((msk ? HUGE_NEG : vv[j]) - cmx[cc + j]) * cinv[cc + j];
      T[cc + j][r] = (_Float16)e;
    }
  }
  __syncthreads();
  int cr = tid >> 2;
  int rc = (tid & 3) * 16;
  _Float16* D = WQ + ((size_t)b * Q_ + q0 + cr) * P_ + p0;
  *(f16x8*)(D + rc) = *(f16x8*)&T[cr][rc];
  *(f16x8*)(D + rc + 8) = *(f16x8*)&T[cr][rc + 8];
}

// ---------------------------------------------------------------------------
// GEMM core v2: 128x128 tile, 4 waves, BK=32, 3-buffer 2-deep prefetch with
// counted vmcnt (never 0 mid-loop), raw barriers, chunk-XOR LDS swizzle
// (source-preswizzled for global_load_lds; same XOR on ds_read).
// C = A(rows i, k-contig, LDA) x B(rows j, k-contig, LDB)^T, fp32 acc.
// ---------------------------------------------------------------------------
template <int NT, int LDA, int LDB>
__device__ __forceinline__ void gemm_core(const _Float16* __restrict__ Ab,
                                          const _Float16* __restrict__ Bb,
                                          _Float16* As, _Float16* Bs,
                                          f32x4 (&acc)[4][4], int w, int l) {
  constexpr int TSZ = 128 * 32;
  int rA = w * 32 + (l >> 2);                       // staged local row
  int sA = ((l & 3) ^ ((rA >> 1) & 3)) * 8;         // swizzled src chunk
  int fr = l & 15;
  int fsw = (((l >> 4) ^ ((fr >> 1) & 3))) * 8;     // swizzled read offset
  int wr = w >> 1, wc = w & 1;

  auto stage = [&](int buf, int t) {
    const _Float16* ga = Ab + (size_t)rA * LDA + t * 32 + sA;
    const _Float16* gb = Bb + (size_t)rA * LDB + t * 32 + sA;
    _Float16* la = As + buf * TSZ + (w * 32) * 32;
    _Float16* lb = Bs + buf * TSZ + (w * 32) * 32;
    dma16(ga, la);
    dma16(ga + 16 * LDA, la + 16 * 32);
    dma16(gb, lb);
    dma16(gb + 16 * LDB, lb + 16 * 32);
  };
  auto compute = [&](int buf) {
    const _Float16* A0 = As + buf * TSZ;
    const _Float16* B0 = Bs + buf * TSZ;
    f16x8 a[4];
#pragma unroll
    for (int m = 0; m < 4; ++m)
      a[m] = *(const f16x8*)(A0 + (wr * 64 + m * 16 + fr) * 32 + fsw);
#pragma unroll
    for (int n = 0; n < 4; ++n) {
      f16x8 bn = *(const f16x8*)(B0 + (wc * 64 + n * 16 + fr) * 32 + fsw);
#pragma unroll
      for (int m = 0; m < 4; ++m)
        acc[m][n] =
            __builtin_amdgcn_mfma_f32_16x16x32_f16(a[m], bn, acc[m][n], 0, 0, 0);
    }
  };

  stage(0, 0);
  stage(1, 1);
  int b0 = 0, b1 = 1, b2 = 2;
#pragma unroll 3
  for (int t = 0; t < NT - 2; ++t) {
    stage(b2, t + 2);
    asm volatile("s_waitcnt vmcnt(8)" ::: "memory");
    __builtin_amdgcn_s_barrier();
    __builtin_amdgcn_sched_barrier(0);
    compute(b0);
    __builtin_amdgcn_s_barrier();
    int tmp = b0; b0 = b1; b1 = b2; b2 = tmp;
  }
  asm volatile("s_waitcnt vmcnt(4)" ::: "memory");
  __builtin_amdgcn_s_barrier();
  __builtin_amdgcn_sched_barrier(0);
  compute(b0);
  __builtin_amdgcn_s_barrier();
  asm volatile("s_waitcnt vmcnt(0)" ::: "memory");
  __builtin_amdgcn_s_barrier();
  __builtin_amdgcn_sched_barrier(0);
  compute(b1);
}

// bijective XCD swizzle (nwg % 8 == 0)
#define SWZ_DECODE(GX, GY)                                          \
  int lin = blockIdx.x + (GX) * (blockIdx.y + (GY) * blockIdx.z);   \
  constexpr int NWG = (GX) * (GY) * B_;                             \
  int w8 = (lin & 7) * (NWG / 8) + (lin >> 3);                      \
  int j0 = (w8 % (GX)) * 128;                                      \
  int t_ = w8 / (GX);                                               \
  int i0 = (t_ % (GY)) * 128;                                       \
  int b = t_ / (GY);

// ---------------------------------------------------------------------------
// K1: qp[b][q][pd] = sum_d q16[q][d] * W16[pd][d]. grid (PD/128, Q/128, B)
// ---------------------------------------------------------------------------
__global__ __launch_bounds__(256) void k1_proj(const _Float16* __restrict__ q16,
                                               const _Float16* __restrict__ W16,
                                               _Float16* __restrict__ qp) {
  __shared__ alignas(16) _Float16 As[3 * 128 * 32];
  __shared__ alignas(16) _Float16 Bs[3 * 128 * 32];
  SWZ_DECODE(PD_ / 128, Q_ / 128)
  int tid = threadIdx.x, w = tid >> 6, l = tid & 63;
  f32x4 acc[4][4];
#pragma unroll
  for (int m = 0; m < 4; ++m)
#pragma unroll
    for (int n = 0; n < 4; ++n) acc[m][n] = (f32x4){0.f, 0.f, 0.f, 0.f};
  gemm_core<QD_ / 32, QD_, QD_>(q16 + (size_t)b * Q_ * QD_ + (size_t)i0 * QD_,
                                W16 + (size_t)j0 * QD_, As, Bs, acc, w, l);
  int wr = w >> 1, wc = w & 1, fr = l & 15, fq = l >> 4;
  _Float16* O = qp + (size_t)b * Q_ * PD_;
#pragma unroll
  for (int m = 0; m < 4; ++m) {
    int rl = wr * 64 + m * 16 + fq * 4;
#pragma unroll
    for (int n = 0; n < 4; ++n) {
      int cl = wc * 64 + n * 16 + fr;
#pragma unroll
      for (int r = 0; r < 4; ++r)
        O[(size_t)(i0 + rl + r) * PD_ + j0 + cl] = (_Float16)acc[m][n][r];
    }
  }
}

// ---------------------------------------------------------------------------
// K2: aff[b][p][q] = sum_d p16[p][d] * qp[q][d]. grid (Q/128, P/128, B)
// Epilogue also computes per-block column stats (over its 128 p-rows with
// pmask) -> pmax_part/psum_part[z = i0/128], replacing the k_colpart pass.
// ---------------------------------------------------------------------------
__global__ __launch_bounds__(256) void k2_aff(const _Float16* __restrict__ p16,
                                              const _Float16* __restrict__ qp,
                                              const int* __restrict__ pmask,
                                              float* __restrict__ aff,
                                              float* __restrict__ pmax_part,
                                              float* __restrict__ psum_part) {
  __shared__ alignas(16) _Float16 As[3 * 128 * 32];
  __shared__ alignas(16) _Float16 Bs[3 * 128 * 32];
  SWZ_DECODE(Q_ / 128, P_ / 128)
  int tid = threadIdx.x, w = tid >> 6, l = tid & 63;
  f32x4 acc[4][4];
#pragma unroll
  for (int m = 0; m < 4; ++m)
#pragma unroll
    for (int n = 0; n < 4; ++n) acc[m][n] = (f32x4){0.f, 0.f, 0.f, 0.f};
  gemm_core<PD_ / 32, PD_, PD_>(p16 + (size_t)b * P_ * PD_ + (size_t)i0 * PD_,
                                qp + (size_t)b * Q_ * PD_ + (size_t)j0 * PD_,
                                As, Bs, acc, w, l);
  int wr = w >> 1, wc = w & 1, fr = l & 15, fq = l >> 4;
  float* Cb = aff + (size_t)b * P_ * Q_;
#pragma unroll
  for (int m = 0; m < 4; ++m) {
    int rl = wr * 64 + m * 16 + fq * 4;
#pragma unroll
    for (int n = 0; n < 4; ++n) {
      int cl = wc * 64 + n * 16 + fr;
#pragma unroll
      for (int r = 0; r < 4; ++r)
        Cb[(size_t)(i0 + rl + r) * Q_ + j0 + cl] = acc[m][n][r];
    }
  }
  // ---- fused column stats over this block's 128 rows ----
  const int* pmb = pmask + b * P_ + i0;
  unsigned pmbits = 0;
#pragma unroll
  for (int m = 0; m < 4; ++m)
#pragma unroll
    for (int r = 0; r < 4; ++r)
      pmbits |= (pmb[wr * 64 + m * 16 + fq * 4 + r] ? 1u : 0u) << (m * 4 + r);
  __syncthreads();  // LDS safe to reuse
  float* redm = (float*)As;  // [2][128]
  float* reds = redm + 256;
#pragma unroll
  for (int n = 0; n < 4; ++n) {
    float ml = -1e30f;
#pragma unroll
    for (int m = 0; m < 4; ++m)
#pragma unroll
      for (int r = 0; r < 4; ++r) {
        float v = ((pmbits >> (m * 4 + r)) & 1) ? HUGE_NEG : acc[m][n][r];
        ml = fmaxf(ml, v);
      }
    float sl = 0.f;
#pragma unroll
    for (int m = 0; m < 4; ++m)
#pragma unroll
      for (int r = 0; r < 4; ++r) {
        float v = ((pmbits >> (m * 4 + r)) & 1) ? HUGE_NEG : acc[m][n][r];
        sl += __expf(v - ml);
      }
#pragma unroll
    for (int off = 16; off <= 32; off <<= 1) {
      float om = __shfl_xor(ml, off);
      float os = __shfl_xor(sl, off);
      float nm = fmaxf(ml, om);
      sl = sl * __expf(ml - nm) + os * __expf(om - nm);
      ml = nm;
    }
    if (fq == 0) {
      int col = wc * 64 + n * 16 + fr;
      redm[wr * 128 + col] = ml;
      reds[wr * 128 + col] = sl;
    }
  }
  __syncthreads();
  if (tid < 128) {
    float m0 = redm[tid], m1 = redm[128 + tid];
    float s0 = reds[tid], s1 = reds[128 + tid];
    float nm = fmaxf(m0, m1);
    float ns = s0 * __expf(m0 - nm) + s1 * __expf(m1 - nm);
    int z = i0 >> 7;
    pmax_part[(b * 8 + z) * Q_ + j0 + tid] = nm;
    psum_part[(b * 8 + z) * Q_ + j0 + tid] = ns;
  }
}

// ---------------------------------------------------------------------------
// K4: out2[b][q][d] = sum_p WQ[q][p] * pT[d][p]  (cinv pre-folded into WQ)
// Also writes candT[b][768+d][q] fp16. grid (PD/128, Q/128, B)
// ---------------------------------------------------------------------------
__global__ __launch_bounds__(256) void k4_attn(const _Float16* __restrict__ WQ,
                                               const _Float16* __restrict__ pT,
                                               float* __restrict__ out2,
                                               _Float16* __restrict__ candT) {
  __shared__ alignas(16) _Float16 As[3 * 128 * 32];
  __shared__ alignas(16) _Float16 Bs[3 * 128 * 32];
  SWZ_DECODE(PD_ / 128, Q_ / 128)
  int tid = threadIdx.x, w = tid >> 6, l = tid & 63;
  f32x4 acc[4][4];
#pragma unroll
  for (int m = 0; m < 4; ++m)
#pragma unroll
    for (int n = 0; n < 4; ++n) acc[m][n] = (f32x4){0.f, 0.f, 0.f, 0.f};
  gemm_core<P_ / 32, P_, P_>(WQ + (size_t)b * Q_ * P_ + (size_t)i0 * P_,
                             pT + (size_t)b * PD_ * P_ + (size_t)j0 * P_, As,
                             Bs, acc, w, l);
  int wr = w >> 1, wc = w & 1, fr = l & 15, fq = l >> 4;
  float* Cb = out2 + (size_t)b * Q_ * PD_;
  _Float16* Tb = candT + (size_t)b * CD_ * Q_;
#pragma unroll
  for (int m = 0; m < 4; ++m) {
    int rl = wr * 64 + m * 16 + fq * 4;
#pragma unroll
    for (int n = 0; n < 4; ++n) {
      int cl = wc * 64 + n * 16 + fr;
      f16x4 cv;
#pragma unroll
      for (int r = 0; r < 4; ++r) {
        float v = acc[m][n][r];
        Cb[(size_t)(i0 + rl + r) * PD_ + j0 + cl] = v;
        cv[r] = (_Float16)v;
      }
      *(f16x4*)(Tb + (size_t)(QD_ + j0 + cl) * Q_ + i0 + rl) = cv;
    }
  }
}

// ---------------------------------------------------------------------------
// K5: out1[b][p][c] = sum_q WP[p][q] * candT[c][q]  (rinv pre-folded into WP)
// grid (CD/128, P/128, B)
// ---------------------------------------------------------------------------
__global__ __launch_bounds__(256) void k5_attn(const _Float16* __restrict__ WP,
                                               const _Float16* __restrict__ candT,
                                               float* __restrict__ out1) {
  __shared__ alignas(16) _Float16 As[3 * 128 * 32];
  __shared__ alignas(16) _Float16 Bs[3 * 128 * 32];
  SWZ_DECODE(CD_ / 128, P_ / 128)
  int tid = threadIdx.x, w = tid >> 6, l = tid & 63;
  f32x4 acc[4][4];
#pragma unroll
  for (int m = 0; m < 4; ++m)
#pragma unroll
    for (int n = 0; n < 4; ++n) acc[m][n] = (f32x4){0.f, 0.f, 0.f, 0.f};
  gemm_core<Q_ / 32, Q_, Q_>(WP + (size_t)b * P_ * Q_ + (size_t)i0 * Q_,
                             candT + (size_t)b * CD_ * Q_ + (size_t)j0 * Q_, As,
                             Bs, acc, w, l);
  int wr = w >> 1, wc = w & 1, fr = l & 15, fq = l >> 4;
  float* Cb = out1 + (size_t)b * P_ * CD_;
#pragma unroll
  for (int m = 0; m < 4; ++m) {
    int rl = wr * 64 + m * 16 + fq * 4;
#pragma unroll
    for (int n = 0; n < 4; ++n) {
      int cl = wc * 64 + n * 16 + fr;
#pragma unroll
      for (int r = 0; r < 4; ++r)
        Cb[(size_t)(i0 + rl + r) * CD_ + j0 + cl] = acc[m][n][r];
    }
  }
}

// ---------------------------------------------------------------------------
extern "C" void kernel_launch(void* const* d_in, const int* in_sizes, int n_in,
                              void* d_out, int out_size, void* d_ws,
                              size_t ws_size, hipStream_t stream) {
  const float* p = (const float*)d_in[0];
  const float* q = (const float*)d_in[1];
  const int* pmask = (const int*)d_in[2];
  const int* qmask = (const int*)d_in[3];
  const float* W = (const float*)d_in[4];
  float* out = (float*)d_out;

  char* ws = (char*)d_ws;
  size_t off = 0;
  auto alloc = [&](size_t bytes) {
    void* r = ws + off;
    off += (bytes + 255) & ~(size_t)255;
    return r;
  };
  // qh16 + qp16 contiguous -> reused as candT [B][CD][Q] fp16 (exact size)
  _Float16* qh16 = (_Float16*)alloc((size_t)B_ * Q_ * QD_ * 2);
  _Float16* qp16 = (_Float16*)alloc((size_t)B_ * Q_ * PD_ * 2);
  _Float16* candT = qh16;
  _Float16* Wh16 = (_Float16*)alloc((size_t)PD_ * QD_ * 2);
  _Float16* ph16 = (_Float16*)alloc((size_t)B_ * P_ * PD_ * 2);  // -> pT
  _Float16* pT = ph16;
  float* aff = (float*)alloc((size_t)B_ * P_ * Q_ * 4);
  _Float16* WP = (_Float16*)alloc((size_t)B_ * P_ * Q_ * 2);
  _Float16* WQ = (_Float16*)alloc((size_t)B_ * Q_ * P_ * 2);
  float* colmax = (float*)alloc((size_t)B_ * Q_ * 4);
  float* colsum = (float*)alloc((size_t)B_ * Q_ * 4);
  float* pmax_part = (float*)alloc((size_t)B_ * 8 * Q_ * 4);
  float* psum_part = (float*)alloc((size_t)B_ * 8 * Q_ * 4);

  float* out1 = out;                          // [B,P,1536]
  float* out2 = out + (size_t)B_ * P_ * CD_;  // [B,Q,768]

  // 1. fp16 conversions
  k_cvt<<<B_ * Q_ * QD_ / 8 / 256, 256, 0, stream>>>(q, qh16, B_ * Q_ * QD_ / 8);
  k_cvt<<<PD_ * QD_ / 8 / 256, 256, 0, stream>>>(W, Wh16, PD_ * QD_ / 8);
  k_cvt<<<B_ * P_ * PD_ / 8 / 256, 256, 0, stream>>>(p, ph16, B_ * P_ * PD_ / 8);
  // 2. K1 projection (fp16)
  k1_proj<<<dim3(PD_ / 128, Q_ / 128, B_), 256, 0, stream>>>(qh16, Wh16, qp16);
  // 3. K2 affinity (fp16 -> fp32 aff) + fused col-stat partials
  k2_aff<<<dim3(Q_ / 128, P_ / 128, B_), 256, 0, stream>>>(
      ph16, qp16, pmask, aff, pmax_part, psum_part);
  // 4. row softmax fused -> WP ; col stats merge
  k_rowWP<<<B_ * P_ / 4, 256, 0, stream>>>(aff, qmask, WP);
  k_colmerge<<<dim3(B_, Q_ / 256), 256, 0, stream>>>(pmax_part, psum_part,
                                                     colmax, colsum);
  // 5. WQ (exp + cinv fold, transposed, fp16)
  k_wq16<<<dim3(P_ / 64, Q_ / 64, B_), 256, 0, stream>>>(aff, pmask, colmax,
                                                         colsum, WQ);
  // 6. pT (fp32 p -> fp16 transposed; aliases ph16, dead after K2)
  k_t2b16<<<dim3(P_ / 64, PD_ / 64, B_), 256, 0, stream>>>(
      p, pT, P_, PD_, (size_t)PD_ * P_, 0);
  // 7. K4 -> out2 + candT upper half
  k4_attn<<<dim3(PD_ / 128, Q_ / 128, B_), 256, 0, stream>>>(WQ, pT, out2,
                                                             candT);
  // 8. candT lower half from q (aliases qh16, dead after K1)
  k_t2b16<<<dim3(Q_ / 64, QD_ / 64, B_), 256, 0, stream>>>(
      q, candT, Q_, QD_, (size_t)CD_ * Q_, 0);
  // 9. K5 -> out1
  k5_attn<<<dim3(CD_ / 128, P_ / 128, B_), 256, 0, stream>>>(WP, candT, out1);
}